// Round 5
// baseline (29122.586 us; speedup 1.0000x reference)
//
#include <hip/hip_runtime.h>
#include <math.h>

#define Bv 256
#define Pv 361
#define Fv 20
#define NROW (Bv*Pv)   // 92416 = 361 * 256

__device__ __forceinline__ float gelu_f(float z){
    return 0.5f*z*(1.0f + erff(z*0.70710678118654752440f));
}

__device__ __forceinline__ void cpb4(float* dst, const float* __restrict__ src, int nfl){
    // nfl: number of floats, multiple of 4, src/dst 16B-aligned
    const float4* s = (const float4*)src;
    float4* d = (float4*)dst;
    for (int i = threadIdx.x; i < (nfl >> 2); i += 256) d[i] = s[i];
}

// out[k] = b[k] + sum_i in[i]*w[i*NOUT+k]   (everything fully unrolled -> registers)
template<int NIN, int NOUT>
__device__ __forceinline__ void dense(const float* __restrict__ sm, int wbase, int bbase,
                                      const float* __restrict__ in, float* __restrict__ out){
    #pragma unroll
    for (int k = 0; k < NOUT; ++k) out[k] = sm[bbase + k];
    #pragma unroll
    for (int i = 0; i < NIN; ++i){
        const float a = in[i];
        const float4* w = (const float4*)&sm[wbase + i*NOUT];
        #pragma unroll
        for (int k4 = 0; k4 < NOUT/4; ++k4){
            float4 ww = w[k4];
            out[4*k4+0] += a*ww.x; out[4*k4+1] += a*ww.y;
            out[4*k4+2] += a*ww.z; out[4*k4+3] += a*ww.w;
        }
    }
}

// out[k] += sum_i in[i]*w[i*NOUT+k]
template<int NIN, int NOUT>
__device__ __forceinline__ void dense_acc(const float* __restrict__ sm, int wbase,
                                          const float* __restrict__ in, float* __restrict__ out){
    #pragma unroll
    for (int i = 0; i < NIN; ++i){
        const float a = in[i];
        const float4* w = (const float4*)&sm[wbase + i*NOUT];
        #pragma unroll
        for (int k4 = 0; k4 < NOUT/4; ++k4){
            float4 ww = w[k4];
            out[4*k4+0] += a*ww.x; out[4*k4+1] += a*ww.y;
            out[4*k4+2] += a*ww.z; out[4*k4+3] += a*ww.w;
        }
    }
}

template<int N>
__device__ __forceinline__ void gelu_v(float* __restrict__ v){
    #pragma unroll
    for (int i = 0; i < N; ++i) v[i] = gelu_f(v[i]);
}

// ---------------- Kernel 1: per-frequency branch+fusion, partial mean over f ----------------
__global__ __launch_bounds__(256, 2) void k_branch(
    const float* __restrict__ x,
    const float* __restrict__ rw1, const float* __restrict__ rb1,
    const float* __restrict__ rw2, const float* __restrict__ rb2,
    const float* __restrict__ rw3, const float* __restrict__ rb3,
    const float* __restrict__ iw1, const float* __restrict__ ib1,
    const float* __restrict__ iw2, const float* __restrict__ ib2,
    const float* __restrict__ iw3, const float* __restrict__ ib3,
    const float* __restrict__ fw1, const float* __restrict__ fb1,
    const float* __restrict__ fw2, const float* __restrict__ fb2,
    float* __restrict__ partial, int nf)
{
    __shared__ __align__(16) float sm[6400];
    enum { RW1=0, RB1=16, RW2=32, RB2=544, RW3=576, RB3=1600,
           IW1=1632, IB1=1648, IW2=1664, IB2=2176, IW3=2208, IB3=3232,
           FW1=3264, FB1=5312, FW2=5344, FB2=6368 };

    const int row = blockIdx.x * 256 + threadIdx.x;
    const int g   = blockIdx.y;
    const float2* __restrict__ x2 = (const float2*)x;

    float acc[32];
    #pragma unroll
    for (int k = 0; k < 32; ++k) acc[k] = 0.f;

    #pragma unroll 1
    for (int ff = 0; ff < nf; ++ff){
        const int f = g*nf + ff;
        __syncthreads();   // protect previous iteration's reads
        cpb4(sm+RW1, rw1+f*16,   16);   cpb4(sm+RB1, rb1+f*16,   16);
        cpb4(sm+RW2, rw2+f*512,  512);  cpb4(sm+RB2, rb2+f*32,   32);
        cpb4(sm+RW3, rw3+f*1024, 1024); cpb4(sm+RB3, rb3+f*32,   32);
        cpb4(sm+IW1, iw1+f*16,   16);   cpb4(sm+IB1, ib1+f*16,   16);
        cpb4(sm+IW2, iw2+f*512,  512);  cpb4(sm+IB2, ib2+f*32,   32);
        cpb4(sm+IW3, iw3+f*1024, 1024); cpb4(sm+IB3, ib3+f*32,   32);
        cpb4(sm+FW1, fw1+f*2048, 2048); cpb4(sm+FB1, fb1+f*32,   32);
        cpb4(sm+FW2, fw2+f*1024, 1024); cpb4(sm+FB2, fb2+f*32,   32);
        __syncthreads();

        const float2 xv = x2[(size_t)row*Fv + f];

        float ro[32];
        {
            float h1[16];
            #pragma unroll
            for (int i = 0; i < 16; ++i) h1[i] = gelu_f(xv.x*sm[RW1+i] + sm[RB1+i]);
            float h2[32];
            dense<16,32>(sm, RW2, RB2, h1, h2);
            gelu_v<32>(h2);
            dense<32,32>(sm, RW3, RB3, h2, ro);
        }
        float io[32];
        {
            float h1[16];
            #pragma unroll
            for (int i = 0; i < 16; ++i) h1[i] = gelu_f(xv.y*sm[IW1+i] + sm[IB1+i]);
            float h2[32];
            dense<16,32>(sm, IW2, IB2, h1, h2);
            gelu_v<32>(h2);
            dense<32,32>(sm, IW3, IB3, h2, io);
        }
        // fusion
        {
            float hf[32];
            dense<32,32>(sm, FW1, FB1, ro, hf);
            dense_acc<32,32>(sm, FW1 + 32*32, io, hf);
            gelu_v<32>(hf);
            #pragma unroll
            for (int k = 0; k < 32; ++k) acc[k] += sm[FB2+k];
            dense_acc<32,32>(sm, FW2, hf, acc);
        }
    }

    float4* o = (float4*)(partial + ((size_t)g*NROW + row)*32);
    #pragma unroll
    for (int k4 = 0; k4 < 8; ++k4)
        o[k4] = make_float4(acc[4*k4+0], acc[4*k4+1], acc[4*k4+2], acc[4*k4+3]);
}

// ---------------- Kernel 2: reduce partials + freq branch + final fusion ----------------
__global__ __launch_bounds__(256, 2) void k_tail(
    const float* __restrict__ x,
    const float* __restrict__ freq_imp,
    const float* __restrict__ pw1, const float* __restrict__ pb1,
    const float* __restrict__ pw2, const float* __restrict__ pb2,
    const float* __restrict__ pw3, const float* __restrict__ pb3,
    const float* __restrict__ gw1, const float* __restrict__ gb1,
    const float* __restrict__ gw2, const float* __restrict__ gb2,
    const float* __restrict__ partial, int ng,
    float* __restrict__ out)
{
    __shared__ __align__(16) float sm[16576];
    const int row = blockIdx.x * 256 + threadIdx.x;

    // softmax(freq_imp) and magnitude-weighted inputs
    float w[20];
    float mx = -1e30f;
    #pragma unroll
    for (int f = 0; f < 20; ++f){ w[f] = freq_imp[f]; mx = fmaxf(mx, w[f]); }
    float s = 0.f;
    #pragma unroll
    for (int f = 0; f < 20; ++f){ w[f] = expf(w[f]-mx); s += w[f]; }
    const float inv = 1.f/s;
    float mw[20];
    const float2* __restrict__ xr = (const float2*)x + (size_t)row*Fv;
    #pragma unroll
    for (int f = 0; f < 20; ++f){
        float2 v = xr[f];
        mw[f] = sqrtf(v.x*v.x + v.y*v.y + 1e-8f) * (w[f]*inv);
    }

    // phase 1: freq MLP weights
    enum { PW1=0, PB1=1280, PW2=1344, PB2=5440, PW3=5504, PB3=7552 };
    cpb4(sm+PW1, pw1, 1280); cpb4(sm+PB1, pb1, 64);
    cpb4(sm+PW2, pw2, 4096); cpb4(sm+PB2, pb2, 64);
    cpb4(sm+PW3, pw3, 2048); cpb4(sm+PB3, pb3, 32);
    __syncthreads();

    float t1[64];
    dense<20,64>(sm, PW1, PB1, mw, t1);
    gelu_v<64>(t1);
    float t2[64];
    dense<64,64>(sm, PW2, PB2, t1, t2);
    gelu_v<64>(t2);
    float ffr[32];
    dense<64,32>(sm, PW3, PB3, t2, ffr);
    __syncthreads();

    // sum partial cf over groups (overlap with phase-2 staging below)
    float acc[32];
    #pragma unroll
    for (int k = 0; k < 32; ++k) acc[k] = 0.f;
    #pragma unroll 1
    for (int g = 0; g < ng; ++g){
        const float4* pg = (const float4*)(partial + ((size_t)g*NROW + row)*32);
        #pragma unroll
        for (int k4 = 0; k4 < 8; ++k4){
            float4 v = pg[k4];
            acc[4*k4+0] += v.x; acc[4*k4+1] += v.y;
            acc[4*k4+2] += v.z; acc[4*k4+3] += v.w;
        }
    }

    // phase 2: final fusion weights (gw1 transposed for contiguous dot reads)
    enum { GW1T=0, GB1=8192, GW2=8320, GB2=16512 };
    for (int idx = threadIdx.x; idx < 8192; idx += 256){
        int j = idx >> 6, i = idx & 63;
        sm[GW1T + idx] = gw1[i*128 + j];
    }
    cpb4(sm+GB1, gb1, 128); cpb4(sm+GW2, gw2, 8192); cpb4(sm+GB2, gb2, 64);
    __syncthreads();

    float u[64];
    #pragma unroll
    for (int k = 0; k < 32; ++k){ u[k] = ffr[k]; u[32+k] = acc[k]*(1.f/20.f); }

    float o[64];
    #pragma unroll
    for (int k = 0; k < 64; ++k) o[k] = sm[GB2+k];

    #pragma unroll 1
    for (int j = 0; j < 128; ++j){
        float d0 = 0.f, d1 = 0.f, d2 = 0.f, d3 = 0.f;
        const float4* wv = (const float4*)&sm[GW1T + j*64];
        #pragma unroll
        for (int i4 = 0; i4 < 16; ++i4){
            float4 ww = wv[i4];
            d0 += u[4*i4+0]*ww.x; d1 += u[4*i4+1]*ww.y;
            d2 += u[4*i4+2]*ww.z; d3 += u[4*i4+3]*ww.w;
        }
        const float d = gelu_f(sm[GB1+j] + ((d0+d1)+(d2+d3)));
        const float4* w2 = (const float4*)&sm[GW2 + j*64];
        #pragma unroll
        for (int k4 = 0; k4 < 16; ++k4){
            float4 ww = w2[k4];
            o[4*k4+0] += d*ww.x; o[4*k4+1] += d*ww.y;
            o[4*k4+2] += d*ww.z; o[4*k4+3] += d*ww.w;
        }
    }

    float4* op = (float4*)(out + (size_t)row*64);
    #pragma unroll
    for (int k4 = 0; k4 < 16; ++k4)
        op[k4] = make_float4(o[4*k4+0], o[4*k4+1], o[4*k4+2], o[4*k4+3]);
}

extern "C" void kernel_launch(void* const* d_in, const int* in_sizes, int n_in,
                              void* d_out, int out_size, void* d_ws, size_t ws_size,
                              hipStream_t stream) {
    (void)in_sizes; (void)n_in; (void)out_size;
    const float* x   = (const float*)d_in[0];
    const float* rw1 = (const float*)d_in[1];  const float* rb1 = (const float*)d_in[2];
    const float* rw2 = (const float*)d_in[3];  const float* rb2 = (const float*)d_in[4];
    const float* rw3 = (const float*)d_in[5];  const float* rb3 = (const float*)d_in[6];
    const float* iw1 = (const float*)d_in[7];  const float* ib1 = (const float*)d_in[8];
    const float* iw2 = (const float*)d_in[9];  const float* ib2 = (const float*)d_in[10];
    const float* iw3 = (const float*)d_in[11]; const float* ib3 = (const float*)d_in[12];
    const float* fw1 = (const float*)d_in[13]; const float* fb1 = (const float*)d_in[14];
    const float* fw2 = (const float*)d_in[15]; const float* fb2 = (const float*)d_in[16];
    const float* fim = (const float*)d_in[17];
    const float* pw1 = (const float*)d_in[18]; const float* pb1 = (const float*)d_in[19];
    const float* pw2 = (const float*)d_in[20]; const float* pb2 = (const float*)d_in[21];
    const float* pw3 = (const float*)d_in[22]; const float* pb3 = (const float*)d_in[23];
    const float* gw1 = (const float*)d_in[24]; const float* gb1 = (const float*)d_in[25];
    const float* gw2 = (const float*)d_in[26]; const float* gb2 = (const float*)d_in[27];
    float* out = (float*)d_out;
    float* partial = (float*)d_ws;

    const size_t per = (size_t)NROW * 32 * sizeof(float);   // 11.83 MB per f-group
    int ng;
    if      (ws_size >= 5*per) ng = 5;
    else if (ws_size >= 4*per) ng = 4;
    else if (ws_size >= 2*per) ng = 2;
    else                       ng = 1;
    const int nf = Fv / ng;

    dim3 g1(361, ng);
    hipLaunchKernelGGL(k_branch, g1, dim3(256), 0, stream,
                       x, rw1, rb1, rw2, rb2, rw3, rb3,
                       iw1, ib1, iw2, ib2, iw3, ib3,
                       fw1, fb1, fw2, fb2, partial, nf);
    hipLaunchKernelGGL(k_tail, dim3(361), dim3(256), 0, stream,
                       x, fim, pw1, pb1, pw2, pb2, pw3, pb3,
                       gw1, gb1, gw2, gb2, partial, ng, out);
}

// Round 8
// 901.518 us; speedup vs baseline: 32.3039x; 32.3039x over previous
//
#include <hip/hip_runtime.h>
#include <math.h>

#define Bv 256
#define Pv 361
#define Fv 20
#define NROW (Bv*Pv)   // 92416 = 361 * 256

// Exact-GELU via A&S 7.1.26 erf polynomial (|err| < 1.5e-7), branch-free,
// guaranteed inline (no ocml call -> no ABI spills around it).
__device__ __forceinline__ float gelu_f(float z){
    const float y  = z * 0.70710678118654752440f;
    const float ax = fabsf(y);
    const float t  = __builtin_amdgcn_rcpf(fmaf(0.3275911f, ax, 1.0f));
    float p = fmaf(1.061405429f, t, -1.453152027f);
    p = fmaf(p, t, 1.421413741f);
    p = fmaf(p, t, -0.284496736f);
    p = fmaf(p, t, 0.254829592f);
    p *= t;
    const float e = __expf(-y*y);
    float er = fmaf(-p, e, 1.0f);          // erf(|y|)
    er = copysignf(er, y);
    return 0.5f * z * (1.0f + er);
}

template<int N>
__device__ __forceinline__ void gelu_v(float* __restrict__ v){
    #pragma unroll
    for (int i = 0; i < N; ++i) v[i] = gelu_f(v[i]);
}

__device__ __forceinline__ void cpb4(float* dst, const float* __restrict__ src, int nfl){
    const float4* s = (const float4*)src;
    float4* d = (float4*)dst;
    for (int i = threadIdx.x; i < (nfl >> 2); i += 256) d[i] = s[i];
}

// out[k] = b[k] + sum_i in[i]*w[i*NOUT+k]  (in[] indexed only by unrolled i)
template<int NIN, int NOUT>
__device__ __forceinline__ void dense(const float* __restrict__ sm, int wbase, int bbase,
                                      const float* __restrict__ in, float* __restrict__ out){
    #pragma unroll
    for (int k = 0; k < NOUT; ++k) out[k] = sm[bbase + k];
    #pragma unroll
    for (int i = 0; i < NIN; ++i){
        const float a = in[i];
        const float4* w = (const float4*)&sm[wbase + i*NOUT];
        #pragma unroll
        for (int k4 = 0; k4 < NOUT/4; ++k4){
            float4 ww = w[k4];
            out[4*k4+0] = fmaf(a, ww.x, out[4*k4+0]);
            out[4*k4+1] = fmaf(a, ww.y, out[4*k4+1]);
            out[4*k4+2] = fmaf(a, ww.z, out[4*k4+2]);
            out[4*k4+3] = fmaf(a, ww.w, out[4*k4+3]);
        }
    }
}

template<int NIN, int NOUT>
__device__ __forceinline__ void dense_acc(const float* __restrict__ sm, int wbase,
                                          const float* __restrict__ in, float* __restrict__ out){
    #pragma unroll
    for (int i = 0; i < NIN; ++i){
        const float a = in[i];
        const float4* w = (const float4*)&sm[wbase + i*NOUT];
        #pragma unroll
        for (int k4 = 0; k4 < NOUT/4; ++k4){
            float4 ww = w[k4];
            out[4*k4+0] = fmaf(a, ww.x, out[4*k4+0]);
            out[4*k4+1] = fmaf(a, ww.y, out[4*k4+1]);
            out[4*k4+2] = fmaf(a, ww.z, out[4*k4+2]);
            out[4*k4+3] = fmaf(a, ww.w, out[4*k4+3]);
        }
    }
}

// LDS layout (floats). Per-branch block stride 1632:
//   W1=0(16) B1=16(16) W2=32(512) B2=544(32) W3T=576(1024, TRANSPOSED [out][in]) B3=1600(32)
// Then FW1=3264(2048) FB1=5312(32) FW2=5344(1024) FB2=6368(32). Total 6400.
#define BST 1632
#define OW1 0
#define OB1 16
#define OW2 32
#define OB2 544
#define OW3T 576
#define OB3 1600
#define OFW1 3264
#define OFB1 5312
#define OFW2 5344
#define OFB2 6368

__global__ __launch_bounds__(256, 2) void k_branch(
    const float* __restrict__ x,
    const float* __restrict__ rw1, const float* __restrict__ rb1,
    const float* __restrict__ rw2, const float* __restrict__ rb2,
    const float* __restrict__ rw3, const float* __restrict__ rb3,
    const float* __restrict__ iw1, const float* __restrict__ ib1,
    const float* __restrict__ iw2, const float* __restrict__ ib2,
    const float* __restrict__ iw3, const float* __restrict__ ib3,
    const float* __restrict__ fw1, const float* __restrict__ fb1,
    const float* __restrict__ fw2, const float* __restrict__ fb2,
    float* __restrict__ partial, int nf)
{
    __shared__ __align__(16) float sm[6400];
    const int tid = threadIdx.x;
    const int row = blockIdx.x * 256 + tid;
    const int g   = blockIdx.y;
    const float2* __restrict__ x2 = (const float2*)x;

    float acc[32];
    #pragma unroll
    for (int k = 0; k < 32; ++k) acc[k] = 0.f;

    #pragma unroll 1
    for (int ff = 0; ff < nf; ++ff){
        const int f = g*nf + ff;
        __syncthreads();   // protect previous iteration's reads
        // real branch weights
        cpb4(sm+0*BST+OW1, rw1+f*16,  16);  cpb4(sm+0*BST+OB1, rb1+f*16,  16);
        cpb4(sm+0*BST+OW2, rw2+f*512, 512); cpb4(sm+0*BST+OB2, rb2+f*32,  32);
        cpb4(sm+0*BST+OB3, rb3+f*32,  32);
        // imag branch weights
        cpb4(sm+1*BST+OW1, iw1+f*16,  16);  cpb4(sm+1*BST+OB1, ib1+f*16,  16);
        cpb4(sm+1*BST+OW2, iw2+f*512, 512); cpb4(sm+1*BST+OB2, ib2+f*32,  32);
        cpb4(sm+1*BST+OB3, ib3+f*32,  32);
        // W3 transposed: W3T[i][k] = W3[k][i]
        for (int t = tid; t < 1024; t += 256){
            sm[0*BST+OW3T+t] = rw3[f*1024 + (t&31)*32 + (t>>5)];
            sm[1*BST+OW3T+t] = iw3[f*1024 + (t&31)*32 + (t>>5)];
        }
        // fusion weights
        cpb4(sm+OFW1, fw1+f*2048, 2048); cpb4(sm+OFB1, fb1+f*32, 32);
        cpb4(sm+OFW2, fw2+f*1024, 1024); cpb4(sm+OFB2, fb2+f*32, 32);
        __syncthreads();

        const float2 xv = x2[(size_t)row*Fv + f];

        float hf[32];
        #pragma unroll
        for (int k = 0; k < 32; ++k) hf[k] = sm[OFB1+k];

        #pragma unroll 1
        for (int br = 0; br < 2; ++br){
            const int wb = br*BST;
            const float xb = br ? xv.y : xv.x;
            float h1[16];
            #pragma unroll
            for (int i = 0; i < 16; ++i)
                h1[i] = gelu_f(fmaf(xb, sm[wb+OW1+i], sm[wb+OB1+i]));
            float h2[32];
            dense<16,32>(sm, wb+OW2, wb+OB2, h1, h2);
            gelu_v<32>(h2);
            // fused: o_i = B3[i] + dot(h2, W3T row i); hf += o_i * FW1[br*32+i, :]
            #pragma unroll 1
            for (int i = 0; i < 32; ++i){
                const float4* wt = (const float4*)&sm[wb + OW3T + i*32];
                float d0=0.f, d1=0.f, d2=0.f, d3=0.f;
                #pragma unroll
                for (int k4 = 0; k4 < 8; ++k4){
                    float4 ww = wt[k4];
                    d0 = fmaf(h2[4*k4+0], ww.x, d0);
                    d1 = fmaf(h2[4*k4+1], ww.y, d1);
                    d2 = fmaf(h2[4*k4+2], ww.z, d2);
                    d3 = fmaf(h2[4*k4+3], ww.w, d3);
                }
                const float oi = sm[wb + OB3 + i] + ((d0+d1)+(d2+d3));
                const float4* wf = (const float4*)&sm[OFW1 + (br*32 + i)*32];
                #pragma unroll
                for (int k4 = 0; k4 < 8; ++k4){
                    float4 ww = wf[k4];
                    hf[4*k4+0] = fmaf(oi, ww.x, hf[4*k4+0]);
                    hf[4*k4+1] = fmaf(oi, ww.y, hf[4*k4+1]);
                    hf[4*k4+2] = fmaf(oi, ww.z, hf[4*k4+2]);
                    hf[4*k4+3] = fmaf(oi, ww.w, hf[4*k4+3]);
                }
            }
        }
        gelu_v<32>(hf);
        #pragma unroll
        for (int k = 0; k < 32; ++k) acc[k] += sm[OFB2+k];
        dense_acc<32,32>(sm, OFW2, hf, acc);
    }

    float4* o = (float4*)(partial + ((size_t)g*NROW + row)*32);
    #pragma unroll
    for (int k4 = 0; k4 < 8; ++k4)
        o[k4] = make_float4(acc[4*k4+0], acc[4*k4+1], acc[4*k4+2], acc[4*k4+3]);
}

// k_tail LDS: phase1 PW1=0(1280) PB1=1280(64) PW2T=1344(4096,TRANSPOSED) PB2=5440(64)
//             PW3=5504(2048) PB3=7552(32)
// phase2 (reuse): GW1T=0(8192,TRANSPOSED) GB1=8192(128) GW2=8320(8192) GB2=16512(64)
__global__ __launch_bounds__(256, 2) void k_tail(
    const float* __restrict__ x,
    const float* __restrict__ freq_imp,
    const float* __restrict__ pw1, const float* __restrict__ pb1,
    const float* __restrict__ pw2, const float* __restrict__ pb2,
    const float* __restrict__ pw3, const float* __restrict__ pb3,
    const float* __restrict__ gw1, const float* __restrict__ gb1,
    const float* __restrict__ gw2, const float* __restrict__ gb2,
    const float* __restrict__ partial, int ng,
    float* __restrict__ out)
{
    __shared__ __align__(16) float sm[16576];
    const int tid = threadIdx.x;
    const int row = blockIdx.x * 256 + tid;

    // softmax(freq_imp), magnitude-weighted inputs
    float w[20];
    float mx = -1e30f;
    #pragma unroll
    for (int f = 0; f < 20; ++f){ w[f] = freq_imp[f]; mx = fmaxf(mx, w[f]); }
    float s = 0.f;
    #pragma unroll
    for (int f = 0; f < 20; ++f){ w[f] = __expf(w[f]-mx); s += w[f]; }
    const float inv = __builtin_amdgcn_rcpf(s);
    float mw[20];
    const float2* __restrict__ xr = (const float2*)x + (size_t)row*Fv;
    #pragma unroll
    for (int f = 0; f < 20; ++f){
        float2 v = xr[f];
        mw[f] = sqrtf(fmaf(v.x,v.x, fmaf(v.y,v.y, 1e-8f))) * (w[f]*inv);
    }

    // phase 1 staging
    enum { PW1=0, PB1=1280, PW2T=1344, PB2=5440, PW3=5504, PB3=7552 };
    cpb4(sm+PW1, pw1, 1280); cpb4(sm+PB1, pb1, 64);
    for (int t = tid; t < 4096; t += 256)
        sm[PW2T + t] = pw2[(t&63)*64 + (t>>6)];     // PW2T[i][k] = pw2[k][i]
    cpb4(sm+PB2, pb2, 64);
    cpb4(sm+PW3, pw3, 2048); cpb4(sm+PB3, pb3, 32);
    __syncthreads();

    float t1[64];
    dense<20,64>(sm, PW1, PB1, mw, t1);
    gelu_v<64>(t1);

    // fused: t2_i = gelu(PB2[i] + dot(t1, PW2T row i)); ffr += t2_i * PW3[i,:]
    float ffr[32];
    #pragma unroll
    for (int k = 0; k < 32; ++k) ffr[k] = sm[PB3+k];
    #pragma unroll 1
    for (int i = 0; i < 64; ++i){
        const float4* wt = (const float4*)&sm[PW2T + i*64];
        float d0=0.f, d1=0.f, d2=0.f, d3=0.f;
        #pragma unroll
        for (int k4 = 0; k4 < 16; ++k4){
            float4 ww = wt[k4];
            d0 = fmaf(t1[4*k4+0], ww.x, d0);
            d1 = fmaf(t1[4*k4+1], ww.y, d1);
            d2 = fmaf(t1[4*k4+2], ww.z, d2);
            d3 = fmaf(t1[4*k4+3], ww.w, d3);
        }
        const float t2i = gelu_f(sm[PB2+i] + ((d0+d1)+(d2+d3)));
        const float4* wp = (const float4*)&sm[PW3 + i*32];
        #pragma unroll
        for (int k4 = 0; k4 < 8; ++k4){
            float4 ww = wp[k4];
            ffr[4*k4+0] = fmaf(t2i, ww.x, ffr[4*k4+0]);
            ffr[4*k4+1] = fmaf(t2i, ww.y, ffr[4*k4+1]);
            ffr[4*k4+2] = fmaf(t2i, ww.z, ffr[4*k4+2]);
            ffr[4*k4+3] = fmaf(t2i, ww.w, ffr[4*k4+3]);
        }
    }
    __syncthreads();

    // sum partials -> aggregated/20
    float acc[32];
    #pragma unroll
    for (int k = 0; k < 32; ++k) acc[k] = 0.f;
    #pragma unroll 1
    for (int g = 0; g < ng; ++g){
        const float4* pg = (const float4*)(partial + ((size_t)g*NROW + row)*32);
        #pragma unroll
        for (int k4 = 0; k4 < 8; ++k4){
            float4 v = pg[k4];
            acc[4*k4+0] += v.x; acc[4*k4+1] += v.y;
            acc[4*k4+2] += v.z; acc[4*k4+3] += v.w;
        }
    }
    #pragma unroll
    for (int k = 0; k < 32; ++k) acc[k] *= (1.f/20.f);

    // phase 2 staging
    enum { GW1T=0, GB1=8192, GW2=8320, GB2=16512 };
    for (int t = tid; t < 8192; t += 256)
        sm[GW1T + t] = gw1[(t&63)*128 + (t>>6)];    // GW1T[j][i] = gw1[i][j]
    cpb4(sm+GB1, gb1, 128); cpb4(sm+GW2, gw2, 8192); cpb4(sm+GB2, gb2, 64);
    __syncthreads();

    // final fusion in two 32-wide output halves (d_j recomputed per half)
    #pragma unroll 1
    for (int half = 0; half < 2; ++half){
        float o[32];
        #pragma unroll
        for (int k = 0; k < 32; ++k) o[k] = sm[GB2 + half*32 + k];
        #pragma unroll 1
        for (int j = 0; j < 128; ++j){
            const float4* wv = (const float4*)&sm[GW1T + j*64];
            float d0=0.f, d1=0.f, d2=0.f, d3=0.f;
            #pragma unroll
            for (int i4 = 0; i4 < 8; ++i4){
                float4 ww = wv[i4];
                d0 = fmaf(ffr[4*i4+0], ww.x, d0);
                d1 = fmaf(ffr[4*i4+1], ww.y, d1);
                d2 = fmaf(ffr[4*i4+2], ww.z, d2);
                d3 = fmaf(ffr[4*i4+3], ww.w, d3);
            }
            #pragma unroll
            for (int i4 = 0; i4 < 8; ++i4){
                float4 ww = wv[8+i4];
                d0 = fmaf(acc[4*i4+0], ww.x, d0);
                d1 = fmaf(acc[4*i4+1], ww.y, d1);
                d2 = fmaf(acc[4*i4+2], ww.z, d2);
                d3 = fmaf(acc[4*i4+3], ww.w, d3);
            }
            const float d = gelu_f(sm[GB1+j] + ((d0+d1)+(d2+d3)));
            const float4* w2 = (const float4*)&sm[GW2 + j*64 + half*32];
            #pragma unroll
            for (int k4 = 0; k4 < 8; ++k4){
                float4 ww = w2[k4];
                o[4*k4+0] = fmaf(d, ww.x, o[4*k4+0]);
                o[4*k4+1] = fmaf(d, ww.y, o[4*k4+1]);
                o[4*k4+2] = fmaf(d, ww.z, o[4*k4+2]);
                o[4*k4+3] = fmaf(d, ww.w, o[4*k4+3]);
            }
        }
        float4* op = (float4*)(out + (size_t)row*64 + half*32);
        #pragma unroll
        for (int k4 = 0; k4 < 8; ++k4)
            op[k4] = make_float4(o[4*k4+0], o[4*k4+1], o[4*k4+2], o[4*k4+3]);
    }
}

extern "C" void kernel_launch(void* const* d_in, const int* in_sizes, int n_in,
                              void* d_out, int out_size, void* d_ws, size_t ws_size,
                              hipStream_t stream) {
    (void)in_sizes; (void)n_in; (void)out_size;
    const float* x   = (const float*)d_in[0];
    const float* rw1 = (const float*)d_in[1];  const float* rb1 = (const float*)d_in[2];
    const float* rw2 = (const float*)d_in[3];  const float* rb2 = (const float*)d_in[4];
    const float* rw3 = (const float*)d_in[5];  const float* rb3 = (const float*)d_in[6];
    const float* iw1 = (const float*)d_in[7];  const float* ib1 = (const float*)d_in[8];
    const float* iw2 = (const float*)d_in[9];  const float* ib2 = (const float*)d_in[10];
    const float* iw3 = (const float*)d_in[11]; const float* ib3 = (const float*)d_in[12];
    const float* fw1 = (const float*)d_in[13]; const float* fb1 = (const float*)d_in[14];
    const float* fw2 = (const float*)d_in[15]; const float* fb2 = (const float*)d_in[16];
    const float* fim = (const float*)d_in[17];
    const float* pw1 = (const float*)d_in[18]; const float* pb1 = (const float*)d_in[19];
    const float* pw2 = (const float*)d_in[20]; const float* pb2 = (const float*)d_in[21];
    const float* pw3 = (const float*)d_in[22]; const float* pb3 = (const float*)d_in[23];
    const float* gw1 = (const float*)d_in[24]; const float* gb1 = (const float*)d_in[25];
    const float* gw2 = (const float*)d_in[26]; const float* gb2 = (const float*)d_in[27];
    float* out = (float*)d_out;
    float* partial = (float*)d_ws;

    const size_t per = (size_t)NROW * 32 * sizeof(float);   // 11.83 MB per f-group
    int ng;
    if      (ws_size >= 5*per) ng = 5;
    else if (ws_size >= 4*per) ng = 4;
    else if (ws_size >= 2*per) ng = 2;
    else                       ng = 1;
    const int nf = Fv / ng;

    dim3 g1(361, ng);
    hipLaunchKernelGGL(k_branch, g1, dim3(256), 0, stream,
                       x, rw1, rb1, rw2, rb2, rw3, rb3,
                       iw1, ib1, iw2, ib2, iw3, ib3,
                       fw1, fb1, fw2, fb2, partial, nf);
    hipLaunchKernelGGL(k_tail, dim3(361), dim3(256), 0, stream,
                       x, fim, pw1, pb1, pw2, pb2, pw3, pb3,
                       gw1, gb1, gw2, gb2, partial, ng, out);
}

// Round 13
// 885.080 us; speedup vs baseline: 32.9039x; 1.0186x over previous
//
#include <hip/hip_runtime.h>
#include <math.h>

#define Bv 256
#define Pv 361
#define Fv 20
#define NROW (Bv*Pv)   // 92416 = 361 * 256

// Exact-GELU via A&S 7.1.26 erf polynomial (|err| < 1.5e-7), branch-free, inline.
__device__ __forceinline__ float gelu_f(float z){
    const float y  = z * 0.70710678118654752440f;
    const float ax = fabsf(y);
    const float t  = __builtin_amdgcn_rcpf(fmaf(0.3275911f, ax, 1.0f));
    float p = fmaf(1.061405429f, t, -1.453152027f);
    p = fmaf(p, t, 1.421413741f);
    p = fmaf(p, t, -0.284496736f);
    p = fmaf(p, t, 0.254829592f);
    p *= t;
    const float e = __expf(-y*y);
    float er = fmaf(-p, e, 1.0f);          // erf(|y|)
    er = copysignf(er, y);
    return 0.5f * z * (1.0f + er);
}

template<int N>
__device__ __forceinline__ void gelu_v(float* __restrict__ v){
    #pragma unroll
    for (int i = 0; i < N; ++i) v[i] = gelu_f(v[i]);
}

__device__ __forceinline__ void cpb4(float* dst, const float* __restrict__ src, int nfl){
    const float4* s = (const float4*)src;
    float4* d = (float4*)dst;
    for (int i = threadIdx.x; i < (nfl >> 2); i += 256) d[i] = s[i];
}

template<int NIN, int NOUT>
__device__ __forceinline__ void dense(const float* __restrict__ sm, int wbase, int bbase,
                                      const float* __restrict__ in, float* __restrict__ out){
    #pragma unroll
    for (int k = 0; k < NOUT; ++k) out[k] = sm[bbase + k];
    #pragma unroll
    for (int i = 0; i < NIN; ++i){
        const float a = in[i];
        const float4* w = (const float4*)&sm[wbase + i*NOUT];
        #pragma unroll
        for (int k4 = 0; k4 < NOUT/4; ++k4){
            float4 ww = w[k4];
            out[4*k4+0] = fmaf(a, ww.x, out[4*k4+0]);
            out[4*k4+1] = fmaf(a, ww.y, out[4*k4+1]);
            out[4*k4+2] = fmaf(a, ww.z, out[4*k4+2]);
            out[4*k4+3] = fmaf(a, ww.w, out[4*k4+3]);
        }
    }
}

template<int NIN, int NOUT>
__device__ __forceinline__ void dense_acc(const float* __restrict__ sm, int wbase,
                                          const float* __restrict__ in, float* __restrict__ out){
    #pragma unroll
    for (int i = 0; i < NIN; ++i){
        const float a = in[i];
        const float4* w = (const float4*)&sm[wbase + i*NOUT];
        #pragma unroll
        for (int k4 = 0; k4 < NOUT/4; ++k4){
            float4 ww = w[k4];
            out[4*k4+0] = fmaf(a, ww.x, out[4*k4+0]);
            out[4*k4+1] = fmaf(a, ww.y, out[4*k4+1]);
            out[4*k4+2] = fmaf(a, ww.z, out[4*k4+2]);
            out[4*k4+3] = fmaf(a, ww.w, out[4*k4+3]);
        }
    }
}

// k_branch per-buffer LDS layout (floats). Per-branch stride 1760:
//  W1 +0(16)  B1 +16(16)  W2 +32(512)  B2 +544(32)
//  W3T +576 (32 rows x 36 pad, W3T[i][k]=W3[k][i])  B3 +1728(32)
// FW1 +3520(2048)  FB1 +5568(32)  FW2 +5600(1024)  FB2 +6624(32). Buffer = 6656.
#define BST  1760
#define OW1  0
#define OB1  16
#define OW2  32
#define OB2  544
#define OW3T 576
#define OB3  1728
#define OFW1 3520
#define OFB1 5568
#define OFW2 5600
#define OFB2 6624
#define BUFSZ 6656

__device__ __forceinline__ void stage_branch(float* b, int f, int tid,
    const float* __restrict__ w1, const float* __restrict__ b1,
    const float* __restrict__ w2, const float* __restrict__ b2,
    const float* __restrict__ w3, const float* __restrict__ b3){
    cpb4(b+OW1, w1+f*16,  16);
    cpb4(b+OB1, b1+f*16,  16);
    cpb4(b+OW2, w2+f*512, 512);
    cpb4(b+OB2, b2+f*32,  32);
    cpb4(b+OB3, b3+f*32,  32);
    // W3 transpose: read global LINEARLY (float4), scatter-write padded LDS rows
    {
        const float4 v = *(const float4*)&w3[f*1024 + tid*4];
        const int t = tid*4; const int k = t>>5; const int i0 = t&31;
        float* dst = b + OW3T + k;
        dst[(i0+0)*36] = v.x; dst[(i0+1)*36] = v.y;
        dst[(i0+2)*36] = v.z; dst[(i0+3)*36] = v.w;
    }
}

__global__ __launch_bounds__(256, 2) void k_branch(
    const float* __restrict__ x,
    const float* __restrict__ rw1, const float* __restrict__ rb1,
    const float* __restrict__ rw2, const float* __restrict__ rb2,
    const float* __restrict__ rw3, const float* __restrict__ rb3,
    const float* __restrict__ iw1, const float* __restrict__ ib1,
    const float* __restrict__ iw2, const float* __restrict__ ib2,
    const float* __restrict__ iw3, const float* __restrict__ ib3,
    const float* __restrict__ fw1, const float* __restrict__ fb1,
    const float* __restrict__ fw2, const float* __restrict__ fb2,
    float* __restrict__ partial, int nf)
{
    __shared__ __align__(16) float sm[2*BUFSZ];
    const int tid = threadIdx.x;
    const int row = blockIdx.x * 256 + tid;
    const int g   = blockIdx.y;
    const float2* __restrict__ x2 = (const float2*)x;

    float acc[32];
    #pragma unroll
    for (int k = 0; k < 32; ++k) acc[k] = 0.f;

    float* ba = sm;          // compute buffer
    float* bb = sm + BUFSZ;  // prefetch buffer

    // prologue: stage f0
    {
        const int f0 = g*nf;
        stage_branch(ba+0,   f0, tid, rw1,rb1,rw2,rb2,rw3,rb3);
        stage_branch(ba+BST, f0, tid, iw1,ib1,iw2,ib2,iw3,ib3);
        cpb4(ba+OFW1, fw1+f0*2048, 2048); cpb4(ba+OFB1, fb1+f0*32, 32);
        cpb4(ba+OFW2, fw2+f0*1024, 1024); cpb4(ba+OFB2, fb2+f0*32, 32);
    }
    __syncthreads();

    #pragma unroll 1
    for (int ff = 0; ff < nf; ++ff){
        const int f = g*nf + ff;
        // prefetch f+1 into the other buffer (overlaps with compute below)
        if (ff + 1 < nf){
            const int fn = f + 1;
            stage_branch(bb+0,   fn, tid, rw1,rb1,rw2,rb2,rw3,rb3);
            stage_branch(bb+BST, fn, tid, iw1,ib1,iw2,ib2,iw3,ib3);
            cpb4(bb+OFW1, fw1+fn*2048, 2048); cpb4(bb+OFB1, fb1+fn*32, 32);
            cpb4(bb+OFW2, fw2+fn*1024, 1024); cpb4(bb+OFB2, fb2+fn*32, 32);
        }

        const float2 xv = x2[(size_t)row*Fv + f];

        float hf[32];
        #pragma unroll
        for (int k = 0; k < 32; ++k) hf[k] = ba[OFB1+k];

        #pragma unroll 1
        for (int br = 0; br < 2; ++br){
            const int wb = br*BST;
            const float xb = br ? xv.y : xv.x;
            float h1[16];
            #pragma unroll
            for (int i = 0; i < 16; ++i)
                h1[i] = gelu_f(fmaf(xb, ba[wb+OW1+i], ba[wb+OB1+i]));
            float h2[32];
            dense<16,32>(ba, wb+OW2, wb+OB2, h1, h2);
            gelu_v<32>(h2);
            // fused: o_i = B3[i] + dot(h2, W3T row i); hf += o_i * FW1[br*32+i, :]
            #pragma unroll 1
            for (int i = 0; i < 32; ++i){
                const float4* wt = (const float4*)&ba[wb + OW3T + i*36];
                float d0=0.f, d1=0.f, d2=0.f, d3=0.f;
                #pragma unroll
                for (int k4 = 0; k4 < 8; ++k4){
                    float4 ww = wt[k4];
                    d0 = fmaf(h2[4*k4+0], ww.x, d0);
                    d1 = fmaf(h2[4*k4+1], ww.y, d1);
                    d2 = fmaf(h2[4*k4+2], ww.z, d2);
                    d3 = fmaf(h2[4*k4+3], ww.w, d3);
                }
                const float oi = ba[wb + OB3 + i] + ((d0+d1)+(d2+d3));
                const float4* wf = (const float4*)&ba[OFW1 + (br*32 + i)*32];
                #pragma unroll
                for (int k4 = 0; k4 < 8; ++k4){
                    float4 ww = wf[k4];
                    hf[4*k4+0] = fmaf(oi, ww.x, hf[4*k4+0]);
                    hf[4*k4+1] = fmaf(oi, ww.y, hf[4*k4+1]);
                    hf[4*k4+2] = fmaf(oi, ww.z, hf[4*k4+2]);
                    hf[4*k4+3] = fmaf(oi, ww.w, hf[4*k4+3]);
                }
            }
        }
        gelu_v<32>(hf);
        #pragma unroll
        for (int k = 0; k < 32; ++k) acc[k] += ba[OFB2+k];
        dense_acc<32,32>(ba, OFW2, hf, acc);

        __syncthreads();           // staging done; all reads of ba done
        float* tmp = ba; ba = bb; bb = tmp;
    }

    float4* o = (float4*)(partial + ((size_t)g*NROW + row)*32);
    #pragma unroll
    for (int k4 = 0; k4 < 8; ++k4)
        o[k4] = make_float4(acc[4*k4+0], acc[4*k4+1], acc[4*k4+2], acc[4*k4+3]);
}

// k_tail LDS: phase1 PW1=0(1280) PB1=1280(64) PW2T=1344(64x68) PB2=5696(64)
//             PW3=5760(2048) PB3=7808(32)
// phase2 (reuse): GW1T=0(128x68) GB1=8704(128) GW2=8832(8192) GB2=17024(64)
__global__ __launch_bounds__(256, 2) void k_tail(
    const float* __restrict__ x,
    const float* __restrict__ freq_imp,
    const float* __restrict__ pw1, const float* __restrict__ pb1,
    const float* __restrict__ pw2, const float* __restrict__ pb2,
    const float* __restrict__ pw3, const float* __restrict__ pb3,
    const float* __restrict__ gw1, const float* __restrict__ gb1,
    const float* __restrict__ gw2, const float* __restrict__ gb2,
    const float* __restrict__ partial, int ng,
    float* __restrict__ out)
{
    __shared__ __align__(16) float sm[17088];
    const int tid = threadIdx.x;
    const int row = blockIdx.x * 256 + tid;

    // softmax(freq_imp), magnitude-weighted inputs
    float w[20];
    float mx = -1e30f;
    #pragma unroll
    for (int f = 0; f < 20; ++f){ w[f] = freq_imp[f]; mx = fmaxf(mx, w[f]); }
    float s = 0.f;
    #pragma unroll
    for (int f = 0; f < 20; ++f){ w[f] = __expf(w[f]-mx); s += w[f]; }
    const float inv = __builtin_amdgcn_rcpf(s);
    float mw[20];
    const float2* __restrict__ xr = (const float2*)x + (size_t)row*Fv;
    #pragma unroll
    for (int f = 0; f < 20; ++f){
        float2 v = xr[f];
        mw[f] = sqrtf(fmaf(v.x,v.x, fmaf(v.y,v.y, 1e-8f))) * (w[f]*inv);
    }

    // phase 1 staging
    enum { PW1=0, PB1=1280, PW2T=1344, PB2=5696, PW3=5760, PB3=7808 };
    cpb4(sm+PW1, pw1, 1280); cpb4(sm+PB1, pb1, 64);
    // PW2 transpose: linear global float4 read, scatter-write pad-68 rows
    for (int t4 = tid; t4 < 1024; t4 += 256){
        float4 v = ((const float4*)pw2)[t4];
        int t = t4*4; int k = t>>6; int i0 = t&63;
        float* dst = sm + PW2T + k;
        dst[(i0+0)*68]=v.x; dst[(i0+1)*68]=v.y; dst[(i0+2)*68]=v.z; dst[(i0+3)*68]=v.w;
    }
    cpb4(sm+PB2, pb2, 64);
    cpb4(sm+PW3, pw3, 2048); cpb4(sm+PB3, pb3, 32);
    __syncthreads();

    float t1[64];
    dense<20,64>(sm, PW1, PB1, mw, t1);
    gelu_v<64>(t1);

    // fused: t2_i = gelu(PB2[i] + dot(t1, PW2T row i)); ffr += t2_i * PW3[i,:]
    float ffr[32];
    #pragma unroll
    for (int k = 0; k < 32; ++k) ffr[k] = sm[PB3+k];
    #pragma unroll 1
    for (int i = 0; i < 64; ++i){
        const float4* wt = (const float4*)&sm[PW2T + i*68];
        float d0=0.f, d1=0.f, d2=0.f, d3=0.f;
        #pragma unroll
        for (int k4 = 0; k4 < 16; ++k4){
            float4 ww = wt[k4];
            d0 = fmaf(t1[4*k4+0], ww.x, d0);
            d1 = fmaf(t1[4*k4+1], ww.y, d1);
            d2 = fmaf(t1[4*k4+2], ww.z, d2);
            d3 = fmaf(t1[4*k4+3], ww.w, d3);
        }
        const float t2i = gelu_f(sm[PB2+i] + ((d0+d1)+(d2+d3)));
        const float4* wp = (const float4*)&sm[PW3 + i*32];
        #pragma unroll
        for (int k4 = 0; k4 < 8; ++k4){
            float4 ww = wp[k4];
            ffr[4*k4+0] = fmaf(t2i, ww.x, ffr[4*k4+0]);
            ffr[4*k4+1] = fmaf(t2i, ww.y, ffr[4*k4+1]);
            ffr[4*k4+2] = fmaf(t2i, ww.z, ffr[4*k4+2]);
            ffr[4*k4+3] = fmaf(t2i, ww.w, ffr[4*k4+3]);
        }
    }

    // sum partials -> aggregated/20 (independent global loads, overlap with above)
    float acc[32];
    #pragma unroll
    for (int k = 0; k < 32; ++k) acc[k] = 0.f;
    #pragma unroll 1
    for (int g = 0; g < ng; ++g){
        const float4* pg = (const float4*)(partial + ((size_t)g*NROW + row)*32);
        #pragma unroll
        for (int k4 = 0; k4 < 8; ++k4){
            float4 v = pg[k4];
            acc[4*k4+0] += v.x; acc[4*k4+1] += v.y;
            acc[4*k4+2] += v.z; acc[4*k4+3] += v.w;
        }
    }
    #pragma unroll
    for (int k = 0; k < 32; ++k) acc[k] *= (1.f/20.f);
    __syncthreads();

    // phase 2 staging (GW1 transpose: linear read, pad-68 scatter write)
    enum { GW1T=0, GB1=8704, GW2=8832, GB2=17024 };
    for (int t4 = tid; t4 < 2048; t4 += 256){
        float4 v = ((const float4*)gw1)[t4];
        int t = t4*4; int i = t>>7; int j0 = t&127;
        float* dst = sm + GW1T + i;
        dst[(j0+0)*68]=v.x; dst[(j0+1)*68]=v.y; dst[(j0+2)*68]=v.z; dst[(j0+3)*68]=v.w;
    }
    cpb4(sm+GB1, gb1, 128); cpb4(sm+GW2, gw2, 8192); cpb4(sm+GB2, gb2, 64);
    __syncthreads();

    // final fusion in two 32-wide output halves (d_j recomputed per half)
    #pragma unroll 1
    for (int half = 0; half < 2; ++half){
        float o[32];
        #pragma unroll
        for (int k = 0; k < 32; ++k) o[k] = sm[GB2 + half*32 + k];
        #pragma unroll 1
        for (int j = 0; j < 128; ++j){
            const float4* wv = (const float4*)&sm[GW1T + j*68];
            float d0=0.f, d1=0.f, d2=0.f, d3=0.f;
            #pragma unroll
            for (int i4 = 0; i4 < 8; ++i4){
                float4 ww = wv[i4];
                d0 = fmaf(ffr[4*i4+0], ww.x, d0);
                d1 = fmaf(ffr[4*i4+1], ww.y, d1);
                d2 = fmaf(ffr[4*i4+2], ww.z, d2);
                d3 = fmaf(ffr[4*i4+3], ww.w, d3);
            }
            #pragma unroll
            for (int i4 = 0; i4 < 8; ++i4){
                float4 ww = wv[8+i4];
                d0 = fmaf(acc[4*i4+0], ww.x, d0);
                d1 = fmaf(acc[4*i4+1], ww.y, d1);
                d2 = fmaf(acc[4*i4+2], ww.z, d2);
                d3 = fmaf(acc[4*i4+3], ww.w, d3);
            }
            const float d = gelu_f(sm[GB1+j] + ((d0+d1)+(d2+d3)));
            const float4* w2 = (const float4*)&sm[GW2 + j*64 + half*32];
            #pragma unroll
            for (int k4 = 0; k4 < 8; ++k4){
                float4 ww = w2[k4];
                o[4*k4+0] = fmaf(d, ww.x, o[4*k4+0]);
                o[4*k4+1] = fmaf(d, ww.y, o[4*k4+1]);
                o[4*k4+2] = fmaf(d, ww.z, o[4*k4+2]);
                o[4*k4+3] = fmaf(d, ww.w, o[4*k4+3]);
            }
        }
        float4* op = (float4*)(out + (size_t)row*64 + half*32);
        #pragma unroll
        for (int k4 = 0; k4 < 8; ++k4)
            op[k4] = make_float4(o[4*k4+0], o[4*k4+1], o[4*k4+2], o[4*k4+3]);
    }
}

extern "C" void kernel_launch(void* const* d_in, const int* in_sizes, int n_in,
                              void* d_out, int out_size, void* d_ws, size_t ws_size,
                              hipStream_t stream) {
    (void)in_sizes; (void)n_in; (void)out_size;
    const float* x   = (const float*)d_in[0];
    const float* rw1 = (const float*)d_in[1];  const float* rb1 = (const float*)d_in[2];
    const float* rw2 = (const float*)d_in[3];  const float* rb2 = (const float*)d_in[4];
    const float* rw3 = (const float*)d_in[5];  const float* rb3 = (const float*)d_in[6];
    const float* iw1 = (const float*)d_in[7];  const float* ib1 = (const float*)d_in[8];
    const float* iw2 = (const float*)d_in[9];  const float* ib2 = (const float*)d_in[10];
    const float* iw3 = (const float*)d_in[11]; const float* ib3 = (const float*)d_in[12];
    const float* fw1 = (const float*)d_in[13]; const float* fb1 = (const float*)d_in[14];
    const float* fw2 = (const float*)d_in[15]; const float* fb2 = (const float*)d_in[16];
    const float* fim = (const float*)d_in[17];
    const float* pw1 = (const float*)d_in[18]; const float* pb1 = (const float*)d_in[19];
    const float* pw2 = (const float*)d_in[20]; const float* pb2 = (const float*)d_in[21];
    const float* pw3 = (const float*)d_in[22]; const float* pb3 = (const float*)d_in[23];
    const float* gw1 = (const float*)d_in[24]; const float* gb1 = (const float*)d_in[25];
    const float* gw2 = (const float*)d_in[26]; const float* gb2 = (const float*)d_in[27];
    float* out = (float*)d_out;
    float* partial = (float*)d_ws;

    const size_t per = (size_t)NROW * 32 * sizeof(float);   // 11.83 MB per f-group
    int ng;
    if      (ws_size >= 5*per) ng = 5;
    else if (ws_size >= 4*per) ng = 4;
    else if (ws_size >= 2*per) ng = 2;
    else                       ng = 1;
    const int nf = Fv / ng;

    dim3 g1(361, ng);
    hipLaunchKernelGGL(k_branch, g1, dim3(256), 0, stream,
                       x, rw1, rb1, rw2, rb2, rw3, rb3,
                       iw1, ib1, iw2, ib2, iw3, ib3,
                       fw1, fb1, fw2, fb2, partial, nf);
    hipLaunchKernelGGL(k_tail, dim3(361), dim3(256), 0, stream,
                       x, fim, pw1, pb1, pw2, pb2, pw3, pb3,
                       gw1, gb1, gw2, gb2, partial, ng, out);
}